// Round 1
// baseline (2916.048 us; speedup 1.0000x reference)
//
#include <hip/hip_runtime.h>
#include <math.h>

namespace {

constexpr float kPI = 3.14159265358979323846f;

// Problem constants: B=32, Y=32, X=32, C=256, M=2, K=4, HQ=16, DV=32.
// q j-index (per a,d,v): j = m*128 + kk*32 + h*2 + p   (256)
// k j-index:             j = kk*32 + h*2 + p           (128)
// v j-index:             j = kk*32 + dv                (128)
// o j-index:             j = (m*4+kk)*32 + dv          (256)  == g*32+dv

template <int AXIS, bool ACCUM>
__global__ __launch_bounds__(512, 1)
void axial_attn_kernel(const float* __restrict__ x,
                       const float* __restrict__ xpos,
                       const float* __restrict__ ypos,
                       const float* __restrict__ Wq,
                       const float* __restrict__ Wk,
                       const float* __restrict__ Wv,
                       const float* __restrict__ bvp,
                       const float* __restrict__ Wo,
                       const float* __restrict__ rfreq,
                       float* __restrict__ out)
{
    __shared__ __align__(16) float xs[32 * 256];      // x line [pos][c]
    __shared__ __align__(16) float csl[32 * 128 * 2]; // [l][m][kk][h][{cos,sin}]
    __shared__ __align__(16) float qbuf[32 * 260];    // q (raw->rotated), later o ; padded row
    __shared__ __align__(16) float kbuf[32 * 256];    // rotated k with m: [pos][m][kk][h][q]
    __shared__ __align__(16) float vbuf[32 * 128];    // [pos][kk][dv]

    const int t = threadIdx.x;
    const int b = blockIdx.x >> 5;
    const int line = blockIdx.x & 31;

    // ---- stage x line ----
    for (int idx = t; idx < 32 * 256; idx += 512) {
        const int p = idx >> 8, c = idx & 255;
        const int gy = (AXIS == 0) ? p : line;
        const int gx = (AXIS == 0) ? line : p;
        xs[idx] = x[((size_t)((b * 32 + gy) * 32 + gx)) * 256 + c];
    }

    // ---- RoPE cos/sin table: phi[l,m,kk,h] ----
    const float* posv = (AXIS == 0) ? ypos : xpos;
    for (int idx = t; idx < 32 * 128; idx += 512) {
        const int l = idx >> 7, r = idx & 127; // r = m*64 + kk*16 + h
        const int h = r & 15;
        const float s0 = kPI / (1.0f + (29.0f / 15.0f) * (float)h);
        const float s1 = kPI / (0.1f + 0.06f * (float)h);
        const float f0 = rfreq[r * 2 + 0] * s0;
        const float f1 = rfreq[r * 2 + 1] * s1;
        const float phi = f0 * posv[l * 2 + 0] + f1 * posv[l * 2 + 1];
        float sv, cv;
        sincosf(phi, &sv, &cv);
        csl[idx * 2 + 0] = cv;
        csl[idx * 2 + 1] = sv;
    }
    __syncthreads();

    // persistent out-projection accumulator: 4 pos x 4 c per thread
    float oacc[4][4] = {{0.f, 0.f, 0.f, 0.f}};
    const int o_ct = t & 63;  // c0 = o_ct*4
    const int o_pt = t >> 6;  // p0 = o_pt*4  (uniform per wave)

    for (int dvi = 0; dvi < 4; ++dvi) {
        const int d = dvi >> 1, v = dvi & 1;
        const int adv = AXIS * 4 + d * 2 + v;
        const float sgn = (d == 0) ? 1.0f : -1.0f;

        // ---- Q projection: qbuf[p][j] = sum_c xs[p][c] * Wq[c][adv][j] ----
        {
            const int jt = t & 63, pt = t >> 6; // pt uniform per wave
            const int j0 = jt * 4, p0 = pt * 4;
            float acc[4][4] = {{0.f, 0.f, 0.f, 0.f}};
            const float* wq = Wq + adv * 256 + j0;
            #pragma unroll 4
            for (int c = 0; c < 256; ++c) {
                const float4 w = *(const float4*)(wq + (size_t)c * 2048);
                #pragma unroll
                for (int i = 0; i < 4; ++i) {
                    const float xv = xs[(p0 + i) * 256 + c];
                    acc[i][0] += xv * w.x; acc[i][1] += xv * w.y;
                    acc[i][2] += xv * w.z; acc[i][3] += xv * w.w;
                }
            }
            #pragma unroll
            for (int i = 0; i < 4; ++i)
                *(float4*)(qbuf + (p0 + i) * 260 + j0) =
                    make_float4(acc[i][0], acc[i][1], acc[i][2], acc[i][3]);
        }

        // ---- K & V projections into registers (share xs reads) ----
        const int kv_jt = t & 31, kv_pt = t >> 5;
        const int kv_j0 = kv_jt * 4, kv_p0 = kv_pt * 2;
        float kacc[2][4] = {{0.f, 0.f, 0.f, 0.f}};
        float vacc[2][4] = {{0.f, 0.f, 0.f, 0.f}};
        {
            const float* wk = Wk + adv * 128 + kv_j0;
            const float* wv = Wv + adv * 128 + kv_j0;
            #pragma unroll 4
            for (int c = 0; c < 256; ++c) {
                const float4 wk4 = *(const float4*)(wk + (size_t)c * 1024);
                const float4 wv4 = *(const float4*)(wv + (size_t)c * 1024);
                #pragma unroll
                for (int i = 0; i < 2; ++i) {
                    const float xv = xs[(kv_p0 + i) * 256 + c];
                    kacc[i][0] += xv * wk4.x; kacc[i][1] += xv * wk4.y;
                    kacc[i][2] += xv * wk4.z; kacc[i][3] += xv * wk4.w;
                    vacc[i][0] += xv * wv4.x; vacc[i][1] += xv * wv4.y;
                    vacc[i][2] += xv * wv4.z; vacc[i][3] += xv * wv4.w;
                }
            }
        }
        __syncthreads(); // qbuf writes visible; prev-iter readers of kbuf/vbuf long done

        // ---- RoPE on q, in place ----
        for (int idx = t; idx < 4096; idx += 512) {
            const int l = idx >> 7, r = idx & 127;
            const float cv = csl[idx * 2], sv = csl[idx * 2 + 1];
            float* qp = qbuf + l * 260 + r * 2;
            const float q0 = qp[0], q1 = qp[1];
            qp[0] = q0 * cv + sgn * q1 * sv;
            qp[1] = -sgn * q0 * sv + q1 * cv;
        }

        // ---- rotate K (adds m) and store; store V (+bv) ----
        {
            const int kk = kv_j0 >> 5;
            const int h0 = (kv_j0 & 31) >> 1; // even; pairs (h0, h0+1), both p
            const float4 bv4 = *(const float4*)(bvp + adv * 128 + kv_j0);
            #pragma unroll
            for (int i = 0; i < 2; ++i) {
                const int p = kv_p0 + i;
                #pragma unroll
                for (int m = 0; m < 2; ++m) {
                    float tmp[4];
                    #pragma unroll
                    for (int hi = 0; hi < 2; ++hi) {
                        const int cidx = p * 128 + m * 64 + kk * 16 + (h0 + hi);
                        const float cv = csl[cidx * 2], sv = csl[cidx * 2 + 1];
                        const float k0 = kacc[i][hi * 2 + 0];
                        const float k1 = kacc[i][hi * 2 + 1];
                        tmp[hi * 2 + 0] = k0 * cv + sgn * k1 * sv;
                        tmp[hi * 2 + 1] = -sgn * k0 * sv + k1 * cv;
                    }
                    *(float4*)(kbuf + p * 256 + m * 128 + kv_j0) =
                        make_float4(tmp[0], tmp[1], tmp[2], tmp[3]);
                }
                *(float4*)(vbuf + p * 128 + kv_j0) =
                    make_float4(vacc[i][0] + bv4.x, vacc[i][1] + bv4.y,
                                vacc[i][2] + bv4.z, vacc[i][3] + bv4.w);
            }
        }
        __syncthreads(); // rotated q, kbuf, vbuf all visible

        // ---- attention: thread = (group g, row u, dv-half) ----
        const int rt = t >> 1, half = t & 1;
        const int g = rt >> 5, u = rt & 31; // g = m*4+kk (uniform per wave)
        const int kk_a = g & 3;
        const int gb = g * 32;

        float qv[32];
        #pragma unroll
        for (int e4 = 0; e4 < 8; ++e4) {
            const float4 q4 = *(const float4*)(qbuf + u * 260 + gb + e4 * 4);
            qv[e4 * 4 + 0] = q4.x; qv[e4 * 4 + 1] = q4.y;
            qv[e4 * 4 + 2] = q4.z; qv[e4 * 4 + 3] = q4.w;
        }
        float orow[16];
        #pragma unroll
        for (int i = 0; i < 16; ++i) orow[i] = 0.f;
        const int vb = kk_a * 32 + half * 16;
        for (int s = 0; s < 32; ++s) {
            const float* kr = kbuf + s * 256 + gb;
            float dot = 0.f;
            #pragma unroll
            for (int e4 = 0; e4 < 8; ++e4) {
                const float4 k4 = *(const float4*)(kr + e4 * 4);
                dot += qv[e4 * 4 + 0] * k4.x + qv[e4 * 4 + 1] * k4.y +
                       qv[e4 * 4 + 2] * k4.z + qv[e4 * 4 + 3] * k4.w;
            }
            const float z = 1.0f / (1.0f + expf(-dot));
            const float* vr = vbuf + s * 128 + vb;
            #pragma unroll
            for (int i4 = 0; i4 < 4; ++i4) {
                const float4 v4 = *(const float4*)(vr + i4 * 4);
                orow[i4 * 4 + 0] += z * v4.x; orow[i4 * 4 + 1] += z * v4.y;
                orow[i4 * 4 + 2] += z * v4.z; orow[i4 * 4 + 3] += z * v4.w;
            }
        }
        __syncthreads(); // all qbuf reads finished before reuse as o-buffer

        // ---- write o into qbuf: o[u][g*32 + dv] ----
        #pragma unroll
        for (int i4 = 0; i4 < 4; ++i4)
            *(float4*)(qbuf + u * 260 + gb + half * 16 + i4 * 4) =
                make_float4(orow[i4 * 4 + 0], orow[i4 * 4 + 1],
                            orow[i4 * 4 + 2], orow[i4 * 4 + 3]);
        __syncthreads();

        // ---- out projection: oacc[p][c] += sum_j o[p][j] * Wo[adv][j][c] ----
        {
            const float* wo = Wo + (size_t)adv * 65536 + o_ct * 4;
            #pragma unroll 4
            for (int j = 0; j < 256; ++j) {
                const float4 w = *(const float4*)(wo + (size_t)j * 256);
                #pragma unroll
                for (int i = 0; i < 4; ++i) {
                    const float ov = qbuf[(o_pt * 4 + i) * 260 + j];
                    oacc[i][0] += ov * w.x; oacc[i][1] += ov * w.y;
                    oacc[i][2] += ov * w.z; oacc[i][3] += ov * w.w;
                }
            }
        }
        if (dvi < 3) __syncthreads(); // before next iter overwrites qbuf
    }

    // ---- write / accumulate output ----
    #pragma unroll
    for (int i = 0; i < 4; ++i) {
        const int p = o_pt * 4 + i;
        const int gy = (AXIS == 0) ? p : line;
        const int gx = (AXIS == 0) ? line : p;
        float* po = out + ((size_t)((b * 32 + gy) * 32 + gx)) * 256 + o_ct * 4;
        if (ACCUM) {
            const float4 old = *(const float4*)po;
            *(float4*)po = make_float4(old.x + oacc[i][0], old.y + oacc[i][1],
                                       old.z + oacc[i][2], old.w + oacc[i][3]);
        } else {
            *(float4*)po = make_float4(oacc[i][0], oacc[i][1],
                                       oacc[i][2], oacc[i][3]);
        }
    }
}

} // namespace

extern "C" void kernel_launch(void* const* d_in, const int* in_sizes, int n_in,
                              void* d_out, int out_size, void* d_ws, size_t ws_size,
                              hipStream_t stream) {
    (void)in_sizes; (void)n_in; (void)out_size; (void)d_ws; (void)ws_size;
    const float* x     = (const float*)d_in[0];
    const float* xpos  = (const float*)d_in[1];
    const float* ypos  = (const float*)d_in[2];
    const float* Wq    = (const float*)d_in[3];
    const float* Wk    = (const float*)d_in[4];
    const float* Wv    = (const float*)d_in[5];
    const float* bv    = (const float*)d_in[6];
    const float* Wo    = (const float*)d_in[7];
    const float* rfreq = (const float*)d_in[8];
    float* out = (float*)d_out;

    // axis 0 (attention over y) writes; axis 1 (over x) accumulates.
    axial_attn_kernel<0, false><<<dim3(1024), dim3(512), 0, stream>>>(
        x, xpos, ypos, Wq, Wk, Wv, bv, Wo, rfreq, out);
    axial_attn_kernel<1, true><<<dim3(1024), dim3(512), 0, stream>>>(
        x, xpos, ypos, Wq, Wk, Wv, bv, Wo, rfreq, out);
}

// Round 2
// 463.064 us; speedup vs baseline: 6.2973x; 6.2973x over previous
//
#include <hip/hip_runtime.h>
#include <math.h>

namespace {

typedef __attribute__((ext_vector_type(8))) short short8;
typedef __attribute__((ext_vector_type(4))) float f32x4;

constexpr float kPI = 3.14159265358979323846f;

__device__ __forceinline__ unsigned short f2bf(float f) {
    unsigned int u = __float_as_uint(f);
    u += 0x7fffu + ((u >> 16) & 1u);
    return (unsigned short)(u >> 16);
}

__device__ __forceinline__ short8 pack8(const float* f) {
    short8 r;
    #pragma unroll
    for (int i = 0; i < 8; ++i) r[i] = (short)f2bf(f[i]);
    return r;
}

// ---- weight pre-arrangement into B-fragment order (bf16) ----
// chunk = (adv, kstep, ntile): 64 lanes x 8 bf16; lane l holds
// B[k = kstep*32 + (l>>4)*8 + i][col = ntile*16 + (l&15)].
__global__ __launch_bounds__(256)
void prep_weights(const float* __restrict__ Wq, const float* __restrict__ Wk,
                  const float* __restrict__ Wv, const float* __restrict__ Wo,
                  short* __restrict__ wsQ, short* __restrict__ wsKV,
                  short* __restrict__ wsO)
{
    const int cid = blockIdx.x * 4 + (threadIdx.x >> 6);
    const int l = threadIdx.x & 63;
    const int lr = l & 15, lk = l >> 4;
    const int arr = cid >> 10, c2 = cid & 1023;
    const int adv = c2 >> 7, ks = (c2 >> 4) & 7, nt = c2 & 15;
    const int c0 = ks * 32 + lk * 8;
    float v[8];
    if (arr == 0) {                       // Wq[c][adv][j], j in [0,256)
        const int j = nt * 16 + lr;
        #pragma unroll
        for (int i = 0; i < 8; ++i)
            v[i] = Wq[((size_t)(c0 + i) * 8 + adv) * 256 + j];
    } else if (arr == 1) {                // K (nt<8) then V (nt>=8), j in [0,128)
        if (nt < 8) {
            const int j = nt * 16 + lr;
            #pragma unroll
            for (int i = 0; i < 8; ++i)
                v[i] = Wk[((size_t)(c0 + i) * 8 + adv) * 128 + j];
        } else {
            const int j = (nt - 8) * 16 + lr;
            #pragma unroll
            for (int i = 0; i < 8; ++i)
                v[i] = Wv[((size_t)(c0 + i) * 8 + adv) * 128 + j];
        }
    } else {                              // Wo[adv][j][c]: k=j, col=c
        const int cc = nt * 16 + lr;
        #pragma unroll
        for (int i = 0; i < 8; ++i)
            v[i] = Wo[((size_t)adv * 256 + (c0 + i)) * 256 + cc];
    }
    short* dst = (arr == 0 ? wsQ : arr == 1 ? wsKV : wsO) + (size_t)c2 * 512 + l * 8;
    *(short8*)dst = pack8(v);
}

// ---- fused per-line axial attention, MFMA GEMMs ----
// block = (b, line); 512 threads = 8 waves.
// Q/KV GEMM: wave w -> j-group w (32 cols), both 16-row tiles.
// O GEMM:    wave w -> c-group w (32 cols), both 16-row tiles.
template <int AXIS, bool ACCUM>
__global__ __launch_bounds__(512, 1)
void axial_attn_mfma(const float* __restrict__ x,
                     const float* __restrict__ xpos,
                     const float* __restrict__ ypos,
                     const float* __restrict__ bvp,
                     const float* __restrict__ rfreq,
                     const short* __restrict__ wsQ,
                     const short* __restrict__ wsKV,
                     const short* __restrict__ wsO,
                     float* __restrict__ out)
{
    __shared__ float csl[32 * 128 * 2];               // [pos][m*64+kk*16+h][{c,s}]
    __shared__ float qbuf[32 * 260];                  // rotated q, fp32, padded
    __shared__ float kbuf[32 * 260];                  // rotated k (with m), padded
    __shared__ float vbuf[32 * 132];                  // v + bias, padded
    __shared__ __align__(16) short obuf[32 * 256];    // attention out, bf16, XOR-swizzled

    const int t = threadIdx.x;
    const int b = blockIdx.x >> 5;
    const int line = blockIdx.x & 31;
    const int w = t >> 6, l = t & 63;
    const int lr = l & 15, lk = l >> 4;

    // RoPE cos/sin table
    const float* posv = (AXIS == 0) ? ypos : xpos;
    for (int idx = t; idx < 32 * 128; idx += 512) {
        const int pos = idx >> 7, r = idx & 127;
        const int h = r & 15;
        const float s0 = kPI / (1.0f + (29.0f / 15.0f) * (float)h);
        const float s1 = kPI / (0.1f + 0.06f * (float)h);
        const float phi = rfreq[r * 2 + 0] * s0 * posv[pos * 2 + 0] +
                          rfreq[r * 2 + 1] * s1 * posv[pos * 2 + 1];
        float sv, cv;
        sincosf(phi, &sv, &cv);
        csl[idx * 2 + 0] = cv;
        csl[idx * 2 + 1] = sv;
    }

    // x-line A-fragments in registers: afr[mtile][kstep], lane l row = mt*16+lr,
    // k = ks*32 + lk*8 + i  (shared by Q-GEMM and KV-GEMM)
    short8 afr[2][8];
    #pragma unroll
    for (int mt = 0; mt < 2; ++mt) {
        const int row = mt * 16 + lr;
        const int gy = (AXIS == 0) ? row : line;
        const int gx = (AXIS == 0) ? line : row;
        const float* px = x + ((size_t)((b * 32 + gy) * 32 + gx)) * 256 + lk * 8;
        #pragma unroll
        for (int ks = 0; ks < 8; ++ks) {
            float tmp[8];
            const float4 a0 = *(const float4*)(px + ks * 32);
            const float4 a1 = *(const float4*)(px + ks * 32 + 4);
            tmp[0] = a0.x; tmp[1] = a0.y; tmp[2] = a0.z; tmp[3] = a0.w;
            tmp[4] = a1.x; tmp[5] = a1.y; tmp[6] = a1.z; tmp[7] = a1.w;
            afr[mt][ks] = pack8(tmp);
        }
    }
    __syncthreads();

    f32x4 oacc[2][2] = {};  // persistent out-projection accumulators (D-frag layout)

    const short8* wsQv  = (const short8*)wsQ;
    const short8* wsKVv = (const short8*)wsKV;
    const short8* wsOv  = (const short8*)wsO;

    for (int dvi = 0; dvi < 4; ++dvi) {
        const int adv = AXIS * 4 + dvi;
        const float sgn = (dvi < 2) ? 1.0f : -1.0f;   // d = dvi>>1

        // ---------- Q projection + in-register RoPE ----------
        {
            f32x4 acc[2][2] = {};
            #pragma unroll
            for (int ks = 0; ks < 8; ++ks) {
                const short8 b0 = wsQv[(size_t)((adv * 8 + ks) * 16 + w * 2 + 0) * 64 + l];
                const short8 b1 = wsQv[(size_t)((adv * 8 + ks) * 16 + w * 2 + 1) * 64 + l];
                acc[0][0] = __builtin_amdgcn_mfma_f32_16x16x32_bf16(afr[0][ks], b0, acc[0][0], 0, 0, 0);
                acc[1][0] = __builtin_amdgcn_mfma_f32_16x16x32_bf16(afr[1][ks], b0, acc[1][0], 0, 0, 0);
                acc[0][1] = __builtin_amdgcn_mfma_f32_16x16x32_bf16(afr[0][ks], b1, acc[0][1], 0, 0, 0);
                acc[1][1] = __builtin_amdgcn_mfma_f32_16x16x32_bf16(afr[1][ks], b1, acc[1][1], 0, 0, 0);
            }
            const int m = w >> 2, kk = w & 3;
            const int p = l & 1;
            #pragma unroll
            for (int mt = 0; mt < 2; ++mt)
                #pragma unroll
                for (int nt = 0; nt < 2; ++nt)
                    #pragma unroll
                    for (int r = 0; r < 4; ++r) {
                        const float own = acc[mt][nt][r];
                        const float oth = __shfl_xor(own, 1);
                        const int pos = mt * 16 + lk * 4 + r;
                        const int jl = nt * 16 + lr;
                        const int h = jl >> 1;
                        const float2 cs = *(const float2*)&csl[(pos * 128 + m * 64 + kk * 16 + h) * 2];
                        const float rv = (p == 0) ? cs.x * own + sgn * cs.y * oth
                                                  : cs.x * own - sgn * cs.y * oth;
                        qbuf[pos * 260 + w * 32 + jl] = rv;
                    }
        }

        // ---------- K/V projection (K waves rotate w/ both m; V waves add bias) ----------
        {
            f32x4 acc[2][2] = {};
            #pragma unroll
            for (int ks = 0; ks < 8; ++ks) {
                const short8 b0 = wsKVv[(size_t)((adv * 8 + ks) * 16 + w * 2 + 0) * 64 + l];
                const short8 b1 = wsKVv[(size_t)((adv * 8 + ks) * 16 + w * 2 + 1) * 64 + l];
                acc[0][0] = __builtin_amdgcn_mfma_f32_16x16x32_bf16(afr[0][ks], b0, acc[0][0], 0, 0, 0);
                acc[1][0] = __builtin_amdgcn_mfma_f32_16x16x32_bf16(afr[1][ks], b0, acc[1][0], 0, 0, 0);
                acc[0][1] = __builtin_amdgcn_mfma_f32_16x16x32_bf16(afr[0][ks], b1, acc[0][1], 0, 0, 0);
                acc[1][1] = __builtin_amdgcn_mfma_f32_16x16x32_bf16(afr[1][ks], b1, acc[1][1], 0, 0, 0);
            }
            if (w < 4) {                    // K: kk = w
                const int p = l & 1;
                #pragma unroll
                for (int mt = 0; mt < 2; ++mt)
                    #pragma unroll
                    for (int nt = 0; nt < 2; ++nt)
                        #pragma unroll
                        for (int r = 0; r < 4; ++r) {
                            const float own = acc[mt][nt][r];
                            const float oth = __shfl_xor(own, 1);
                            const int pos = mt * 16 + lk * 4 + r;
                            const int jl = nt * 16 + lr;
                            const int h = jl >> 1;
                            #pragma unroll
                            for (int m2 = 0; m2 < 2; ++m2) {
                                const float2 cs = *(const float2*)&csl[(pos * 128 + m2 * 64 + w * 16 + h) * 2];
                                const float rv = (p == 0) ? cs.x * own + sgn * cs.y * oth
                                                          : cs.x * own - sgn * cs.y * oth;
                                kbuf[pos * 260 + m2 * 128 + w * 32 + jl] = rv;
                            }
                        }
            } else {                        // V: kk = w-4, j = (w-4)*32 + nt*16 + lr
                #pragma unroll
                for (int nt = 0; nt < 2; ++nt) {
                    const float bvv = bvp[adv * 128 + (w - 4) * 32 + nt * 16 + lr];
                    #pragma unroll
                    for (int mt = 0; mt < 2; ++mt)
                        #pragma unroll
                        for (int r = 0; r < 4; ++r) {
                            const int pos = mt * 16 + lk * 4 + r;
                            vbuf[pos * 132 + (w - 4) * 32 + nt * 16 + lr] = acc[mt][nt][r] + bvv;
                        }
                }
            }
        }
        __syncthreads();

        // ---------- attention: lane pair (half) splits the 32-dot and the dv range ----------
        {
            const int rt = t >> 1, half = t & 1;
            const int g = rt >> 5, u = rt & 31;       // g uniform per wave
            const int qb = g * 32 + half * 16;
            float qv[16];
            #pragma unroll
            for (int i = 0; i < 16; i += 4) {
                const float4 q4 = *(const float4*)&qbuf[u * 260 + qb + i];
                qv[i] = q4.x; qv[i + 1] = q4.y; qv[i + 2] = q4.z; qv[i + 3] = q4.w;
            }
            float orow[16];
            #pragma unroll
            for (int i = 0; i < 16; ++i) orow[i] = 0.f;
            const int vb = (g & 3) * 32 + half * 16;
            #pragma unroll 2
            for (int s = 0; s < 32; ++s) {
                const float* kr = &kbuf[s * 260 + qb];
                float d0 = 0.f, d1 = 0.f;
                #pragma unroll
                for (int i = 0; i < 16; i += 8) {
                    const float4 k4 = *(const float4*)(kr + i);
                    const float4 k5 = *(const float4*)(kr + i + 4);
                    d0 += qv[i] * k4.x + qv[i + 1] * k4.y + qv[i + 2] * k4.z + qv[i + 3] * k4.w;
                    d1 += qv[i + 4] * k5.x + qv[i + 5] * k5.y + qv[i + 6] * k5.z + qv[i + 7] * k5.w;
                }
                float dot = d0 + d1;
                dot += __shfl_xor(dot, 1);
                const float z = __builtin_amdgcn_rcpf(1.0f + __expf(-dot));
                const float* vr = &vbuf[s * 132 + vb];
                #pragma unroll
                for (int i = 0; i < 16; i += 4) {
                    const float4 v4 = *(const float4*)(vr + i);
                    orow[i] += z * v4.x; orow[i + 1] += z * v4.y;
                    orow[i + 2] += z * v4.z; orow[i + 3] += z * v4.w;
                }
            }
            // write o as bf16, XOR-swizzled rows for conflict-free A-frag reads
            #pragma unroll
            for (int i2 = 0; i2 < 2; ++i2) {
                const short8 pk = pack8(&orow[i2 * 8]);
                int byteoff = u * 512 + qb * 2 + i2 * 16;
                byteoff ^= (u & 7) << 4;
                *(short8*)((char*)obuf + byteoff) = pk;
            }
        }
        __syncthreads();

        // ---------- out projection: oacc += o(bf16) x Wo_frag ----------
        {
            #pragma unroll
            for (int ks = 0; ks < 8; ++ks) {
                int bo0 = (lr * 512 + (ks * 32 + lk * 8) * 2) ^ ((lr & 7) << 4);
                int bo1 = ((16 + lr) * 512 + (ks * 32 + lk * 8) * 2) ^ ((lr & 7) << 4);
                const short8 a0 = *(const short8*)((const char*)obuf + bo0);
                const short8 a1 = *(const short8*)((const char*)obuf + bo1);
                const short8 b0 = wsOv[(size_t)((adv * 8 + ks) * 16 + w * 2 + 0) * 64 + l];
                const short8 b1 = wsOv[(size_t)((adv * 8 + ks) * 16 + w * 2 + 1) * 64 + l];
                oacc[0][0] = __builtin_amdgcn_mfma_f32_16x16x32_bf16(a0, b0, oacc[0][0], 0, 0, 0);
                oacc[1][0] = __builtin_amdgcn_mfma_f32_16x16x32_bf16(a1, b0, oacc[1][0], 0, 0, 0);
                oacc[0][1] = __builtin_amdgcn_mfma_f32_16x16x32_bf16(a0, b1, oacc[0][1], 0, 0, 0);
                oacc[1][1] = __builtin_amdgcn_mfma_f32_16x16x32_bf16(a1, b1, oacc[1][1], 0, 0, 0);
            }
        }
        // next-iteration writes to qbuf/kbuf/vbuf are fenced by the barriers above;
        // obuf is rewritten only after the next S1 barrier -> no extra sync needed
    }

    // ---------- write / accumulate output ----------
    #pragma unroll
    for (int mt = 0; mt < 2; ++mt)
        #pragma unroll
        for (int nt = 0; nt < 2; ++nt)
            #pragma unroll
            for (int r = 0; r < 4; ++r) {
                const int pos = mt * 16 + lk * 4 + r;
                const int c = w * 32 + nt * 16 + lr;
                const int gy = (AXIS == 0) ? pos : line;
                const int gx = (AXIS == 0) ? line : pos;
                float* po = out + ((size_t)((b * 32 + gy) * 32 + gx)) * 256 + c;
                if (ACCUM) *po += oacc[mt][nt][r];
                else       *po = oacc[mt][nt][r];
            }
}

} // namespace

extern "C" void kernel_launch(void* const* d_in, const int* in_sizes, int n_in,
                              void* d_out, int out_size, void* d_ws, size_t ws_size,
                              hipStream_t stream) {
    (void)in_sizes; (void)n_in; (void)out_size; (void)ws_size;
    const float* x     = (const float*)d_in[0];
    const float* xpos  = (const float*)d_in[1];
    const float* ypos  = (const float*)d_in[2];
    const float* Wq    = (const float*)d_in[3];
    const float* Wk    = (const float*)d_in[4];
    const float* Wv    = (const float*)d_in[5];
    const float* bv    = (const float*)d_in[6];
    const float* Wo    = (const float*)d_in[7];
    const float* rfreq = (const float*)d_in[8];
    float* out = (float*)d_out;

    short* wsQ  = (short*)d_ws;                 // 1 MB
    short* wsKV = wsQ + 1024 * 512;             // 1 MB
    short* wsO  = wsKV + 1024 * 512;            // 1 MB

    prep_weights<<<dim3(768), dim3(256), 0, stream>>>(Wq, Wk, Wv, Wo, wsQ, wsKV, wsO);
    axial_attn_mfma<0, false><<<dim3(1024), dim3(512), 0, stream>>>(
        x, xpos, ypos, bv, rfreq, wsQ, wsKV, wsO, out);
    axial_attn_mfma<1, true><<<dim3(1024), dim3(512), 0, stream>>>(
        x, xpos, ypos, bv, rfreq, wsQ, wsKV, wsO, out);
}